// Round 1
// baseline (114.259 us; speedup 1.0000x reference)
//
#include <hip/hip_runtime.h>
#include <hip/hip_bf16.h>

// Problem constants
#define B    2
#define CIN  256
#define H    56
#define W    56
#define OUTC 256
#define KS   7
#define PAD  3
#define G    8
#define CG   32
#define HP   62           // H + 2*PAD
#define WP   62
#define P1   (H * W)      // 3136
#define P2   (HP * WP)    // 3844

typedef __attribute__((ext_vector_type(2))) _Float16 h2;
typedef __attribute__((ext_vector_type(8))) _Float16 f16x8;
typedef __attribute__((ext_vector_type(8))) unsigned short ushort8;
typedef __attribute__((ext_vector_type(4))) float f32x4;

__device__ inline unsigned short f2h(float f) {    // RNE float->fp16 bits
    const _Float16 h = (_Float16)f;
    return *(const unsigned short*)&h;
}

__device__ inline float fdot2(h2 a, h2 b, float c) {
#if defined(__has_builtin)
#if __has_builtin(__builtin_amdgcn_fdot2)
    return __builtin_amdgcn_fdot2(a, b, c, false);
#else
    return c + (float)a[0] * (float)b[0] + (float)a[1] * (float)b[1];
#endif
#else
    return c + (float)a[0] * (float)b[0] + (float)a[1] * (float)b[1];
#endif
}

__device__ inline float dot8(const f16x8 q, const f16x8 k, float s) {
    s = fdot2((h2){q[0], q[1]}, (h2){k[0], k[1]}, s);
    s = fdot2((h2){q[2], q[3]}, (h2){k[2], k[3]}, s);
    s = fdot2((h2){q[4], q[5]}, (h2){k[4], k[5]}, s);
    s = fdot2((h2){q[6], q[7]}, (h2){k[6], k[7]}, s);
    return s;
}

// ---------------------------------------------------------------------------
// Fused fp32->fp16 + MFMA GEMM (one launch): grid (31, 6, B).  (unchanged)
//   y<2  : q GEMM  (w_q x fm_t1), x<25 only (N=P1)
//   y>=2 : kv GEMM (w_k rows 0..255, w_v rows 256..511 x padded fm_t0, N=P2)
// 128x128 tile, 4 waves, BK=32; staging converts fp32 inputs inline.
// Epilogue writes fp16 INTERLEAVED planes: base[((b*8+g)*4+sub)*Pstr + n]*8+l8.
// ---------------------------------------------------------------------------
#define ASTR 40
__global__ __launch_bounds__(256, 2) void gemm_kernel(const float* __restrict__ fm,
                                                      const float* __restrict__ wq,
                                                      const float* __restrict__ wk,
                                                      const float* __restrict__ wv,
                                                      unsigned short* __restrict__ qi,
                                                      unsigned short* __restrict__ ki,
                                                      unsigned short* __restrict__ vi) {
    const int b = blockIdx.z;
    const bool isQ = blockIdx.y < 2;
    if (isQ && blockIdx.x >= 25) return;
    const int o0 = (isQ ? blockIdx.y : (blockIdx.y - 2)) * 128;   // 0..383
    const int n0 = blockIdx.x * 128;
    const int Nreal = isQ ? P1 : P2;
    const int Pstr  = isQ ? P1 : P2;

    const float* Wsrc;
    int orow0;
    if (isQ)            { Wsrc = wq; orow0 = o0; }
    else if (o0 < 256)  { Wsrc = wk; orow0 = o0; }
    else                { Wsrc = wv; orow0 = o0 - 256; }

    __shared__ unsigned short Alds[128 * ASTR];
    __shared__ unsigned short Blds[128 * ASTR];
    const int tid = threadIdx.x;
    const int lane = tid & 63;
    const int wave = tid >> 6;
    const int wr = (wave >> 1) * 64;
    const int wc = (wave & 1) * 64;
    const int lrow = lane & 15;
    const int quad = lane >> 4;

    const int arow = tid & 127;
    const int akc  = (tid >> 7) * 16;

    const int n = n0 + arow;
    int srcoff = -1;
    if (isQ) {
        if (n < P1) srcoff = n;
    } else {
        if (n < P2) {
            const int y = n / WP, x = n - y * WP;
            const int iy = y - PAD, ix = x - PAD;
            if (iy >= 0 && iy < H && ix >= 0 && ix < W) srcoff = iy * W + ix;
        }
    }
    const float* fmB = fm + ((size_t)b * (2 * CIN) + (isQ ? CIN : 0)) * P1;
    const float* wrow = Wsrc + (size_t)orow0 * CIN + (size_t)arow * CIN + akc;

    unsigned short* alp = Alds + arow * ASTR + akc;
    unsigned short* blp = Blds + arow * ASTR + akc;

    f32x4 acc[4][4] = {};

    float av[16], bv[16];
    {
        const float4 a0 = ((const float4*)wrow)[0];
        const float4 a1 = ((const float4*)wrow)[1];
        const float4 a2 = ((const float4*)wrow)[2];
        const float4 a3 = ((const float4*)wrow)[3];
        av[0]=a0.x; av[1]=a0.y; av[2]=a0.z; av[3]=a0.w;
        av[4]=a1.x; av[5]=a1.y; av[6]=a1.z; av[7]=a1.w;
        av[8]=a2.x; av[9]=a2.y; av[10]=a2.z; av[11]=a2.w;
        av[12]=a3.x; av[13]=a3.y; av[14]=a3.z; av[15]=a3.w;
        #pragma unroll
        for (int j = 0; j < 16; ++j)
            bv[j] = (srcoff >= 0) ? fmB[(size_t)(akc + j) * P1 + srcoff] : 0.f;
    }

    for (int kb = 0; kb < CIN / 32; ++kb) {
        {
            f16x8 p0, p1, p2, p3;
            #pragma unroll
            for (int j = 0; j < 8; ++j) {
                p0[j] = (_Float16)av[j];
                p1[j] = (_Float16)av[8 + j];
                p2[j] = (_Float16)bv[j];
                p3[j] = (_Float16)bv[8 + j];
            }
            *(f16x8*)(alp)     = p0;
            *(f16x8*)(alp + 8) = p1;
            *(f16x8*)(blp)     = p2;
            *(f16x8*)(blp + 8) = p3;
        }
        __syncthreads();
        if (kb < CIN / 32 - 1) {
            const int c0 = (kb + 1) * 32 + akc;
            const float* wnext = wrow + (kb + 1) * 32;
            const float4 a0 = ((const float4*)wnext)[0];
            const float4 a1 = ((const float4*)wnext)[1];
            const float4 a2 = ((const float4*)wnext)[2];
            const float4 a3 = ((const float4*)wnext)[3];
            av[0]=a0.x; av[1]=a0.y; av[2]=a0.z; av[3]=a0.w;
            av[4]=a1.x; av[5]=a1.y; av[6]=a1.z; av[7]=a1.w;
            av[8]=a2.x; av[9]=a2.y; av[10]=a2.z; av[11]=a2.w;
            av[12]=a3.x; av[13]=a3.y; av[14]=a3.z; av[15]=a3.w;
            #pragma unroll
            for (int j = 0; j < 16; ++j)
                bv[j] = (srcoff >= 0) ? fmB[(size_t)(c0 + j) * P1 + srcoff] : 0.f;
        }
        f16x8 af[4], bfr[4];
        #pragma unroll
        for (int mi = 0; mi < 4; ++mi)
            af[mi] = *(const f16x8*)&Alds[(wr + mi * 16 + lrow) * ASTR + quad * 8];
        #pragma unroll
        for (int ni = 0; ni < 4; ++ni)
            bfr[ni] = *(const f16x8*)&Blds[(wc + ni * 16 + lrow) * ASTR + quad * 8];
        #pragma unroll
        for (int mi = 0; mi < 4; ++mi)
            #pragma unroll
            for (int ni = 0; ni < 4; ++ni)
                acc[mi][ni] = __builtin_amdgcn_mfma_f32_16x16x32_f16(af[mi], bfr[ni], acc[mi][ni], 0, 0, 0);
        __syncthreads();
    }

    #pragma unroll
    for (int mi = 0; mi < 4; ++mi) {
        const int gmBase = o0 + wr + mi * 16 + quad * 4;
        int ch0;
        unsigned short* base;
        if (isQ)               { ch0 = gmBase;       base = qi; }
        else if (gmBase < 256) { ch0 = gmBase;       base = ki; }
        else                   { ch0 = gmBase - 256; base = vi; }
        const int g   = ch0 >> 5;
        const int sub = (ch0 >> 3) & 3;
        const int l8  = ch0 & 7;
        unsigned short* pbase = base + ((((size_t)b * 8 + g) * 4 + sub) * Pstr) * 8 + l8;
        #pragma unroll
        for (int ni = 0; ni < 4; ++ni) {
            const int gn = n0 + wc + ni * 16 + lrow;
            if (gn < Nreal) {
                ushort4 pk;
                pk.x = f2h(acc[mi][ni][0]);
                pk.y = f2h(acc[mi][ni][1]);
                pk.z = f2h(acc[mi][ni][2]);
                pk.w = f2h(acc[mi][ni][3]);
                *(ushort4*)(pbase + (size_t)gn * 8) = pk;
            }
        }
    }
}

// ---------------------------------------------------------------------------
// Grouped 7x7 attention v3: barrier-free, LDS-free, one thread per pixel.
// K/V intermediates (~8 MB total) are L2/LLC-resident; each thread streams
// its 7x7 window (4 subs x 49 taps x 16B) directly from global. Adjacent
// lanes = adjacent pixels -> coalesced 16B/lane loads with strong L1 reuse
// across the 7 j-taps. 49 independent accumulator chains per thread give
// the scheduler deep ILP/MLP; no __syncthreads anywhere.
// Grid: (ceil(P1/256)=13, G, B) = 208 blocks x 4 waves = 832 waves.
// rel_h/rel_w are uniform per block (g = blockIdx.y) -> SGPR loads.
// ---------------------------------------------------------------------------
__global__ __launch_bounds__(256) void attn_kernel(const unsigned short* __restrict__ qi,
                                                   const unsigned short* __restrict__ ki,
                                                   const unsigned short* __restrict__ vi,
                                                   const float* __restrict__ rel_h,
                                                   const float* __restrict__ rel_w,
                                                   float* __restrict__ out) {
    const int b = blockIdx.z;
    const int g = blockIdx.y;
    const int tid = threadIdx.x;

    int p = blockIdx.x * 256 + tid;
    const bool act = p < P1;
    if (!act) p = P1 - 1;              // clamp: loads stay in-bounds, stores skipped

    const int h = p / W;
    const int w = p - h * W;
    const int pos0 = h * WP + w;       // window origin in padded 62x62 grid
    const size_t bg4 = ((size_t)b * G + g) * 4;

    // ---- load q (32 channels as 4x f16x8) ----
    f16x8 qh[4];
    #pragma unroll
    for (int s = 0; s < 4; ++s)
        qh[s] = *(const f16x8*)(qi + ((bg4 + s) * P1 + p) * 8);

    // ---- bias: bd[t] = sum_c q[c] * rel[c,t]  (rel is uniform -> SGPR) ----
    const float* rel = (g < 4) ? (rel_h + (size_t)g * CG * KS)
                               : (rel_w + (size_t)(g - 4) * CG * KS);
    float bd[KS];
    #pragma unroll
    for (int t = 0; t < KS; ++t) {
        float s0 = 0.f;
        #pragma unroll
        for (int s = 0; s < 4; ++s)
            #pragma unroll
            for (int j = 0; j < 8; ++j)
                s0 += (float)qh[s][j] * rel[(s * 8 + j) * KS + t];
        bd[t] = s0;
    }

    float logits[KS * KS];
    #pragma unroll
    for (int i = 0; i < KS; ++i)
        #pragma unroll
        for (int j = 0; j < KS; ++j)
            logits[i * KS + j] = (g < 4) ? bd[i] : bd[j];

    // ---- QK^T: 4 subs x 49 taps, direct global reads (L1/L2 hits) ----
    #pragma unroll
    for (int s = 0; s < 4; ++s) {
        const unsigned short* kp = ki + ((bg4 + s) * P2 + pos0) * 8;
        const f16x8 q = qh[s];
        #pragma unroll
        for (int i = 0; i < KS; ++i) {
            const unsigned short* kr = kp + i * WP * 8;
            #pragma unroll
            for (int j = 0; j < KS; ++j) {
                const f16x8 kv = *(const f16x8*)(kr + j * 8);
                logits[i * KS + j] = dot8(q, kv, logits[i * KS + j]);
            }
        }
    }

    // ---- softmax over 49 taps ----
    {
        float m = logits[0];
        #pragma unroll
        for (int t = 1; t < KS * KS; ++t) m = fmaxf(m, logits[t]);
        float sum = 0.f;
        #pragma unroll
        for (int t = 0; t < KS * KS; ++t) {
            const float e = __expf(logits[t] - m);
            logits[t] = e;
            sum += e;
        }
        const float inv = 1.f / sum;
        #pragma unroll
        for (int t = 0; t < KS * KS; ++t) logits[t] *= inv;
    }

    // ---- PV: per sub, 8-channel fp32 accumulate (v_fma_mix), then store ----
    #pragma unroll
    for (int s = 0; s < 4; ++s) {
        const unsigned short* vp = vi + ((bg4 + s) * P2 + pos0) * 8;
        float a[8] = {};
        #pragma unroll
        for (int i = 0; i < KS; ++i) {
            const unsigned short* vr = vp + i * WP * 8;
            #pragma unroll
            for (int j = 0; j < KS; ++j) {
                const f16x8 vv = *(const f16x8*)(vr + j * 8);
                const float wt = logits[i * KS + j];
                #pragma unroll
                for (int c = 0; c < 8; ++c)
                    a[c] += wt * (float)vv[c];
            }
        }
        if (act) {
            float* op = out + ((size_t)b * OUTC + g * CG + s * 8) * P1 + p;
            #pragma unroll
            for (int c = 0; c < 8; ++c)
                op[(size_t)c * P1] = a[c];
        }
    }
}

extern "C" void kernel_launch(void* const* d_in, const int* in_sizes, int n_in,
                              void* d_out, int out_size, void* d_ws, size_t ws_size,
                              hipStream_t stream) {
    const float* fm = (const float*)d_in[0];
    const float* wq = (const float*)d_in[1];
    const float* wk = (const float*)d_in[2];
    const float* wv = (const float*)d_in[3];
    const float* rh = (const float*)d_in[4];
    const float* rw = (const float*)d_in[5];
    float* out = (float*)d_out;

    unsigned short* ws = (unsigned short*)d_ws;
    unsigned short* qi = ws;                             // 2*8*4*3136*8 fp16
    unsigned short* ki = qi + (size_t)B * OUTC * P1;     // 2*8*4*3844*8 fp16
    unsigned short* vi = ki + (size_t)B * OUTC * P2;

    gemm_kernel<<<dim3(31, 6, B), 256, 0, stream>>>(fm, wq, wk, wv, qi, ki, vi);
    attn_kernel<<<dim3((P1 + 255) / 256, G, B), 256, 0, stream>>>(qi, ki, vi, rh, rw, out);
}